// Round 1
// baseline (158.065 us; speedup 1.0000x reference)
//
#include <hip/hip_runtime.h>

// HDDTBinaryLoss: loss = mean((t - sigmoid(x))^2 * dist), dist = sum of 4
// exact squared EDTs (p-mask, ~p-mask, t-mask, ~t-mask), B=8,C=1,H=W=256.
//
// K1 (scan_cols): column scans (axis H), fwd+bwd, distances stored uint16.
//   D layout: plane = dir*4 + src*2 + comp  (dir: 0 fwd / 1 bwd; src: 0 p / 1 t;
//   comp: 0 mask / 1 ~mask);  D[((plane*8 + b) << 16) + (h << 8) + w]
//   Needs 8 planes * 8 batches * 65536 * 2B = 8 MiB of d_ws.
// K2 (envelope): per (b,row): g2[k] = min(fwd,bwd)^2 in LDS as float4 (4 masks),
//   brute-force lower envelope over k (W=256), weight by (t-p)^2, block-reduce,
//   atomicAdd scaled partial into d_out (zeroed by K1 thread 0).

#define HW 65536
#define BIGF 512.0f

__global__ __launch_bounds__(256) void scan_cols(const float* __restrict__ inp,
                                                 const int* __restrict__ tgt,
                                                 unsigned short* __restrict__ D,
                                                 float* __restrict__ out) {
    int gid = blockIdx.x * 256 + threadIdx.x;
    if (gid == 0) out[0] = 0.0f;   // harness poisons d_out before timed replays

    int w   = gid & 255;
    int b   = (gid >> 8) & 7;
    int src = (gid >> 11) & 1;     // 0: p = sigmoid(inp) mask (inp > 0); 1: target mask
    int dir = (gid >> 12) & 1;     // 0: top->bottom; 1: bottom->top

    const int base = b * HW + w;
    unsigned short* D0 = D + ((((size_t)(dir * 4 + src * 2 + 0) * 8 + b) << 16) + w);
    unsigned short* D1 = D + ((((size_t)(dir * 4 + src * 2 + 1) * 8 + b) << 16) + w);

    float c0 = BIGF;  // distance-since-last-False for mask
    float c1 = BIGF;  // ... for complement mask
    #pragma unroll 16
    for (int it = 0; it < 256; ++it) {
        int h = dir ? (255 - it) : it;
        bool m;
        if (src == 0) m = inp[base + (h << 8)] > 0.0f;   // sigmoid(x)>0.5 <=> x>0
        else          m = tgt[base + (h << 8)] > 0;      // t>0.5 <=> target==1
        c0 = m ? c0 + 1.0f : 0.0f;
        c1 = m ? 0.0f : c1 + 1.0f;
        D0[h << 8] = (unsigned short)c0;
        D1[h << 8] = (unsigned short)c1;
    }
}

__global__ __launch_bounds__(256) void envelope(const float* __restrict__ inp,
                                                const int* __restrict__ tgt,
                                                const unsigned short* __restrict__ D,
                                                float* __restrict__ out) {
    __shared__ float4 sg2[256];
    __shared__ float wsum[4];

    int bi = blockIdx.x;     // 0..2047
    int b  = bi >> 8;
    int i  = bi & 255;
    int j  = threadIdx.x;
    int rowoff = (i << 8) + j;

    // Stage g2 = min(fwd,bwd)^2 for the 4 masks, interleaved so one
    // ds_read_b128 broadcast per k fetches all four in the main loop.
    float g2v[4];
    #pragma unroll
    for (int mm = 0; mm < 4; ++mm) {
        unsigned int f  = D[(((size_t)(mm)     * 8 + b) << 16) + rowoff];
        unsigned int bw = D[(((size_t)(4 + mm) * 8 + b) << 16) + rowoff];
        float g = (float)(f < bw ? f : bw);
        g2v[mm] = g * g;
    }
    sg2[j] = make_float4(g2v[0], g2v[1], g2v[2], g2v[3]);
    __syncthreads();

    float a0 = 1e30f, a1 = 1e30f, a2 = 1e30f, a3 = 1e30f;
    float jf = (float)j;
    #pragma unroll 4
    for (int k = 0; k < 256; ++k) {
        float4 g2k = sg2[k];            // uniform address -> LDS broadcast
        float d = jf - (float)k;
        a0 = fminf(a0, fmaf(d, d, g2k.x));
        a1 = fminf(a1, fmaf(d, d, g2k.y));
        a2 = fminf(a2, fmaf(d, d, g2k.z));
        a3 = fminf(a3, fmaf(d, d, g2k.w));
    }
    float dist = (a0 + a1) + (a2 + a3);

    float x = inp[(b << 16) + rowoff];
    float t = (float)tgt[(b << 16) + rowoff];
    float p = 1.0f / (1.0f + __expf(-x));
    float e = t - p;
    float v = e * e * dist;

    // block reduction: wave64 shuffle, then cross-wave via LDS
    #pragma unroll
    for (int off = 32; off > 0; off >>= 1) v += __shfl_down(v, off);
    if ((j & 63) == 0) wsum[j >> 6] = v;
    __syncthreads();
    if (j == 0) {
        float s = (wsum[0] + wsum[1]) + (wsum[2] + wsum[3]);
        atomicAdd(out, s * (1.0f / 524288.0f));   // / (B*C*H*W) = 8*65536
    }
}

extern "C" void kernel_launch(void* const* d_in, const int* in_sizes, int n_in,
                              void* d_out, int out_size, void* d_ws, size_t ws_size,
                              hipStream_t stream) {
    const float* inp = (const float*)d_in[0];
    const int*   tgt = (const int*)d_in[1];
    unsigned short* D = (unsigned short*)d_ws;   // needs 8 MiB
    float* out = (float*)d_out;

    scan_cols<<<32, 256, 0, stream>>>(inp, tgt, D, out);
    envelope<<<2048, 256, 0, stream>>>(inp, tgt, D, out);
}

// Round 2
// 87.271 us; speedup vs baseline: 1.8112x; 1.8112x over previous
//
#include <hip/hip_runtime.h>

// HDDTBinaryLoss: loss = mean((t - sigmoid(x))^2 * dist), dist = sum of 4
// exact squared EDTs (p>0.5, ~p, t>0.5, ~t), B=8, C=1, H=W=256.
//
// Round 2 structure:
//  K1 build_masks: per (src,b,64-row word) build column occupancy bitmasks.
//     BM[src][b][wd][w] : u64, bit h = mask true at row wd*64+h, col w. 128 KB.
//  K2 envelope: block = (b, 4 rows). Stage g2[row][k][4 masks] in LDS directly
//     from bitmasks (1-D EDT via clz/ffs: up = i-lastzero(<=i), down =
//     firstzero(>=i)-i; sentinels lz=-513, fz=768 reproduce ref BIG=512 carry).
//     Then brute-force lower envelope over k; each thread computes 4 pixels
//     (j0+64q) per ds_read_b128 broadcast -> LDS issue 4x below VALU work.
//     Weight by (t-p)^2, block-reduce, atomicAdd into d_out.

#define IMG 65536

// Squared 1-D column EDT at row i from the mask's ZERO-set bits (z word w
// covers rows 64w..64w+63; bit set = pixel is False for the mask).
__device__ __forceinline__ float g2_from_words(unsigned long long z0,
                                               unsigned long long z1,
                                               unsigned long long z2,
                                               unsigned long long z3,
                                               int i) {
    int wi = i >> 6, bi = i & 63;
    unsigned long long lowm  = (~0ULL) >> (63 - bi);  // bits 0..bi
    unsigned long long highm = (~0ULL) << bi;         // bits bi..63
    unsigned long long z[4] = {z0, z1, z2, z3};

    int lz = -513;  // no zero above => fwd = i + 513  (ref: BIG + i + 1)
    #pragma unroll
    for (int w = 0; w < 4; ++w) {
        unsigned long long m = z[w];
        if (w == wi) m &= lowm;
        if (w >  wi) m = 0;
        if (m) lz = (w << 6) + 63 - __clzll(m);
    }
    int fz = 768;   // no zero below => bwd = 768 - i  (ref: BIG + (255-i) + 1)
    #pragma unroll
    for (int w = 3; w >= 0; --w) {
        unsigned long long m = z[w];
        if (w == wi) m &= highm;
        if (w <  wi) m = 0;
        if (m) fz = (w << 6) + (__ffsll(m) - 1);
    }
    int u = i - lz, d = fz - i;
    float g = (float)(u < d ? u : d);
    return g * g;
}

__global__ __launch_bounds__(256) void build_masks(const float* __restrict__ inp,
                                                   const int* __restrict__ tgt,
                                                   unsigned long long* __restrict__ BM,
                                                   float* __restrict__ out) {
    int bid = blockIdx.x;            // 64 blocks: src = bid>>5, b = (bid>>2)&7, wd = bid&3
    int w   = threadIdx.x;           // column
    if (bid == 0 && w == 0) out[0] = 0.0f;   // d_out is poisoned before every replay

    int src = bid >> 5;
    int b   = (bid >> 2) & 7;
    int wd  = bid & 3;
    int base = b * IMG + (wd << 6) * 256 + w;

    unsigned long long word = 0;
    if (src == 0) {
        #pragma unroll
        for (int h = 0; h < 64; ++h)                 // sigmoid(x)>0.5 <=> x>0
            word |= ((unsigned long long)(inp[base + (h << 8)] > 0.0f)) << h;
    } else {
        #pragma unroll
        for (int h = 0; h < 64; ++h)
            word |= ((unsigned long long)(tgt[base + (h << 8)] > 0)) << h;
    }
    BM[(((size_t)src * 8 + b) * 4 + wd) * 256 + w] = word;
}

__global__ __launch_bounds__(256) void envelope(const float* __restrict__ inp,
                                                const int* __restrict__ tgt,
                                                const unsigned long long* __restrict__ BM,
                                                float* __restrict__ out) {
    __shared__ float4 sg2[4][256];   // [row in tile][k] = g2 of 4 masks
    __shared__ float wsum[4];

    int b  = blockIdx.x >> 6;        // 512 blocks: 8 b x 64 row-tiles
    int r0 = (blockIdx.x & 63) << 2;
    int t  = threadIdx.x;

    // ---- stage g2 from bitmasks: thread t = column t, all 4 rows ----
    {
        unsigned long long bp[4], bt[4];
        #pragma unroll
        for (int wd = 0; wd < 4; ++wd) {
            bp[wd] = BM[(((size_t)0 * 8 + b) * 4 + wd) * 256 + t];
            bt[wd] = BM[(((size_t)1 * 8 + b) * 4 + wd) * 256 + t];
        }
        #pragma unroll
        for (int rr = 0; rr < 4; ++rr) {
            int i = r0 + rr;
            float g0 = g2_from_words(~bp[0], ~bp[1], ~bp[2], ~bp[3], i); // p-mask
            float g1 = g2_from_words( bp[0],  bp[1],  bp[2],  bp[3], i); // ~p
            float g2 = g2_from_words(~bt[0], ~bt[1], ~bt[2], ~bt[3], i); // t-mask
            float g3 = g2_from_words( bt[0],  bt[1],  bt[2],  bt[3], i); // ~t
            sg2[rr][t] = make_float4(g0, g1, g2, g3);
        }
    }
    __syncthreads();

    // ---- lower envelope: wave r handles row r0+r, lane j0 pixels j0+64q ----
    int r  = t >> 6;
    int j0 = t & 63;
    float a[4][4];                   // [mask][q]
    #pragma unroll
    for (int m = 0; m < 4; ++m)
        #pragma unroll
        for (int q = 0; q < 4; ++q) a[m][q] = 1e30f;

    float j0f = (float)j0;
    #pragma unroll 4
    for (int k = 0; k < 256; ++k) {
        float4 g = sg2[r][k];        // uniform address -> LDS broadcast
        float d0 = j0f - (float)k;
        float d1 = d0 + 64.0f, d2 = d0 + 128.0f, d3 = d0 + 192.0f;
        a[0][0] = fminf(a[0][0], fmaf(d0, d0, g.x));
        a[1][0] = fminf(a[1][0], fmaf(d0, d0, g.y));
        a[2][0] = fminf(a[2][0], fmaf(d0, d0, g.z));
        a[3][0] = fminf(a[3][0], fmaf(d0, d0, g.w));
        a[0][1] = fminf(a[0][1], fmaf(d1, d1, g.x));
        a[1][1] = fminf(a[1][1], fmaf(d1, d1, g.y));
        a[2][1] = fminf(a[2][1], fmaf(d1, d1, g.z));
        a[3][1] = fminf(a[3][1], fmaf(d1, d1, g.w));
        a[0][2] = fminf(a[0][2], fmaf(d2, d2, g.x));
        a[1][2] = fminf(a[1][2], fmaf(d2, d2, g.y));
        a[2][2] = fminf(a[2][2], fmaf(d2, d2, g.z));
        a[3][2] = fminf(a[3][2], fmaf(d2, d2, g.w));
        a[0][3] = fminf(a[0][3], fmaf(d3, d3, g.x));
        a[1][3] = fminf(a[1][3], fmaf(d3, d3, g.y));
        a[2][3] = fminf(a[2][3], fmaf(d3, d3, g.z));
        a[3][3] = fminf(a[3][3], fmaf(d3, d3, g.w));
    }

    // ---- weight by (t - sigmoid(x))^2 and reduce ----
    int rowbase = b * IMG + ((r0 + r) << 8);
    float v = 0.0f;
    #pragma unroll
    for (int q = 0; q < 4; ++q) {
        int j = j0 + (q << 6);
        float dist = (a[0][q] + a[1][q]) + (a[2][q] + a[3][q]);
        float x  = inp[rowbase + j];
        float tt = (float)tgt[rowbase + j];
        float p  = 1.0f / (1.0f + __expf(-x));
        float e  = tt - p;
        v = fmaf(e * e, dist, v);
    }

    #pragma unroll
    for (int off = 32; off > 0; off >>= 1) v += __shfl_down(v, off);
    if ((t & 63) == 0) wsum[t >> 6] = v;
    __syncthreads();
    if (t == 0) {
        float s = (wsum[0] + wsum[1]) + (wsum[2] + wsum[3]);
        atomicAdd(out, s * (1.0f / 524288.0f));   // / (B*H*W)
    }
}

extern "C" void kernel_launch(void* const* d_in, const int* in_sizes, int n_in,
                              void* d_out, int out_size, void* d_ws, size_t ws_size,
                              hipStream_t stream) {
    const float* inp = (const float*)d_in[0];
    const int*   tgt = (const int*)d_in[1];
    unsigned long long* BM = (unsigned long long*)d_ws;   // 128 KiB
    float* out = (float*)d_out;

    build_masks<<<64, 256, 0, stream>>>(inp, tgt, BM, out);
    envelope<<<512, 256, 0, stream>>>(inp, tgt, BM, out);
}

// Round 3
// 69.322 us; speedup vs baseline: 2.2801x; 1.2589x over previous
//
#include <hip/hip_runtime.h>

// HDDTBinaryLoss: loss = mean((t - sigmoid(x))^2 * dist), dist = sum of 4
// exact squared EDTs (p>0.5, ~p, t>0.5, ~t), B=8, C=1, H=W=256.
//
// Round 3 structure:
//  K1 build_masks (256 blocks): column occupancy bitmasks as 16-bit partials.
//     PM u16[ (((src*8+b)*4+wd)*256 + w)*4 + q ]  -- little-endian, so the 4
//     q-partials alias to the same u64 word (bit h = row wd*64+h, col w) the
//     envelope reads. 128 KiB of d_ws.
//  K2 envelope (512 blocks, block = (b, 4 rows)):
//     - stage g2[row][k][4 masks] in LDS from bitmasks (clz/ffs 1-D EDT,
//       sentinels reproduce ref BIG=512 carry exactly; absmax 0.0 in R2).
//     - EXACT adaptive envelope: dt2[j] = min_k (j-k)^2 + g2[k]. Iterate by
//       offset kk = k-j so s = kk^2 is wave-uniform. Window |kk|<=2 (includes
//       kk=0 => own-column g2, a hard upper bound U), then R = floor(sqrt(U))+1
//       wave-maxed -> uniform loop kk=3..R. Pruned kk have kk^2 >= U so they
//       provably cannot improve the min -> exact for ANY input; random 50/50
//       masks give R ~ 3-6 so the 256-wide scan collapses to a handful.
//     - weight by (t-p)^2, block-reduce, atomicAdd into d_out.

#define IMG 65536

// Squared 1-D column EDT at row i from the mask's ZERO-set bits (z word w
// covers rows 64w..64w+63; bit set = pixel is False for the mask).
__device__ __forceinline__ float g2_from_words(unsigned long long z0,
                                               unsigned long long z1,
                                               unsigned long long z2,
                                               unsigned long long z3,
                                               int i) {
    int wi = i >> 6, bi = i & 63;
    unsigned long long lowm  = (~0ULL) >> (63 - bi);  // bits 0..bi
    unsigned long long highm = (~0ULL) << bi;         // bits bi..63
    unsigned long long z[4] = {z0, z1, z2, z3};

    int lz = -513;  // no zero above => fwd = i + 513  (ref: BIG + i + 1)
    #pragma unroll
    for (int w = 0; w < 4; ++w) {
        unsigned long long m = z[w];
        if (w == wi) m &= lowm;
        if (w >  wi) m = 0;
        if (m) lz = (w << 6) + 63 - __clzll(m);
    }
    int fz = 768;   // no zero below => bwd = 768 - i  (ref: BIG + (255-i) + 1)
    #pragma unroll
    for (int w = 3; w >= 0; --w) {
        unsigned long long m = z[w];
        if (w == wi) m &= highm;
        if (w <  wi) m = 0;
        if (m) fz = (w << 6) + (__ffsll(m) - 1);
    }
    int u = i - lz, d = fz - i;
    float g = (float)(u < d ? u : d);
    return g * g;
}

__global__ __launch_bounds__(256) void build_masks(const float* __restrict__ inp,
                                                   const int* __restrict__ tgt,
                                                   unsigned short* __restrict__ PM,
                                                   float* __restrict__ out) {
    int bid = blockIdx.x;   // 256 blocks: src=bid>>7, b=(bid>>4)&7, wd=(bid>>2)&3, q=bid&3
    int w   = threadIdx.x;  // column
    if (bid == 0 && w == 0) out[0] = 0.0f;   // d_out is poisoned before every replay

    int src = bid >> 7;
    int b   = (bid >> 4) & 7;
    int wd  = (bid >> 2) & 3;
    int q   = bid & 3;
    int h0  = (wd << 6) + (q << 4);
    int base = b * IMG + (h0 << 8) + w;

    unsigned int word = 0;
    if (src == 0) {
        #pragma unroll
        for (int hh = 0; hh < 16; ++hh)              // sigmoid(x)>0.5 <=> x>0
            word |= ((unsigned int)(inp[base + (hh << 8)] > 0.0f)) << hh;
    } else {
        #pragma unroll
        for (int hh = 0; hh < 16; ++hh)
            word |= ((unsigned int)(tgt[base + (hh << 8)] > 0)) << hh;
    }
    PM[((((size_t)src * 8 + b) * 4 + wd) * 256 + w) * 4 + q] = (unsigned short)word;
}

__global__ __launch_bounds__(256) void envelope(const float* __restrict__ inp,
                                                const int* __restrict__ tgt,
                                                const unsigned long long* __restrict__ BM,
                                                float* __restrict__ out) {
    __shared__ float4 sg2[4][256];   // [row in tile][k] = g2 of 4 masks
    __shared__ float wsum[4];

    int b  = blockIdx.x >> 6;        // 512 blocks: 8 b x 64 row-tiles
    int r0 = (blockIdx.x & 63) << 2;
    int t  = threadIdx.x;

    // ---- stage g2 from bitmasks: thread t = column t, all 4 rows ----
    {
        unsigned long long bp[4], bt[4];
        #pragma unroll
        for (int wd = 0; wd < 4; ++wd) {
            bp[wd] = BM[(((size_t)0 * 8 + b) * 4 + wd) * 256 + t];
            bt[wd] = BM[(((size_t)1 * 8 + b) * 4 + wd) * 256 + t];
        }
        #pragma unroll
        for (int rr = 0; rr < 4; ++rr) {
            int i = r0 + rr;
            float g0 = g2_from_words(~bp[0], ~bp[1], ~bp[2], ~bp[3], i); // p-mask
            float g1 = g2_from_words( bp[0],  bp[1],  bp[2],  bp[3], i); // ~p
            float g2 = g2_from_words(~bt[0], ~bt[1], ~bt[2], ~bt[3], i); // t-mask
            float g3 = g2_from_words( bt[0],  bt[1],  bt[2],  bt[3], i); // ~t
            sg2[rr][t] = make_float4(g0, g1, g2, g3);
        }
    }
    __syncthreads();

    // ---- adaptive exact lower envelope: wave r = row r0+r, lane j0, 4 pixels ----
    int r  = t >> 6;
    int j0 = t & 63;
    float a[4][4];                   // [mask][q]
    #pragma unroll
    for (int m = 0; m < 4; ++m)
        #pragma unroll
        for (int q = 0; q < 4; ++q) a[m][q] = 1e30f;

    // window |kk| <= 2 (includes kk=0: own-column g2 -> hard upper bound)
    #pragma unroll
    for (int kk = -2; kk <= 2; ++kk) {
        float s = (float)(kk * kk);
        #pragma unroll
        for (int q = 0; q < 4; ++q) {
            int k = j0 + (q << 6) + kk;
            k = min(max(k, 0), 255);                 // clamped k is a valid candidate
            float4 g = sg2[r][k];                    // stride-1 ds_read_b128
            a[0][q] = fminf(a[0][q], g.x + s);
            a[1][q] = fminf(a[1][q], g.y + s);
            a[2][q] = fminf(a[2][q], g.z + s);
            a[3][q] = fminf(a[3][q], g.w + s);
        }
    }

    // prune radius: kk^2 >= U can't improve any entry of this lane
    float U = 0.0f;
    #pragma unroll
    for (int m = 0; m < 4; ++m)
        #pragma unroll
        for (int q = 0; q < 4; ++q) U = fmaxf(U, a[m][q]);
    int R = (int)sqrtf(U) + 1;       // +1 guards fp rounding; values are exact ints
    R = min(R, 255);
    #pragma unroll
    for (int off = 1; off < 64; off <<= 1) R = max(R, __shfl_xor(R, off));

    for (int kk = 3; kk <= R; ++kk) {                // wave-uniform, no divergence
        float s = (float)(kk * kk);
        #pragma unroll
        for (int q = 0; q < 4; ++q) {
            int kl = max(j0 + (q << 6) - kk, 0);
            int kr = min(j0 + (q << 6) + kk, 255);
            float4 gl = sg2[r][kl];
            float4 gr = sg2[r][kr];
            a[0][q] = fminf(a[0][q], fminf(gl.x, gr.x) + s);
            a[1][q] = fminf(a[1][q], fminf(gl.y, gr.y) + s);
            a[2][q] = fminf(a[2][q], fminf(gl.z, gr.z) + s);
            a[3][q] = fminf(a[3][q], fminf(gl.w, gr.w) + s);
        }
    }

    // ---- weight by (t - sigmoid(x))^2 and reduce ----
    int rowbase = b * IMG + ((r0 + r) << 8);
    float v = 0.0f;
    #pragma unroll
    for (int q = 0; q < 4; ++q) {
        int j = j0 + (q << 6);
        float dist = (a[0][q] + a[1][q]) + (a[2][q] + a[3][q]);
        float x  = inp[rowbase + j];
        float tt = (float)tgt[rowbase + j];
        float p  = 1.0f / (1.0f + __expf(-x));
        float e  = tt - p;
        v = fmaf(e * e, dist, v);
    }

    #pragma unroll
    for (int off = 32; off > 0; off >>= 1) v += __shfl_down(v, off);
    if ((t & 63) == 0) wsum[t >> 6] = v;
    __syncthreads();
    if (t == 0) {
        float s = (wsum[0] + wsum[1]) + (wsum[2] + wsum[3]);
        atomicAdd(out, s * (1.0f / 524288.0f));   // / (B*H*W)
    }
}

extern "C" void kernel_launch(void* const* d_in, const int* in_sizes, int n_in,
                              void* d_out, int out_size, void* d_ws, size_t ws_size,
                              hipStream_t stream) {
    const float* inp = (const float*)d_in[0];
    const int*   tgt = (const int*)d_in[1];
    unsigned short* PM = (unsigned short*)d_ws;            // 128 KiB
    const unsigned long long* BM = (const unsigned long long*)d_ws;
    float* out = (float*)d_out;

    build_masks<<<256, 256, 0, stream>>>(inp, tgt, PM, out);
    envelope<<<512, 256, 0, stream>>>(inp, tgt, BM, out);
}